// Round 4
// baseline (715.868 us; speedup 1.0000x reference)
//
#include <hip/hip_runtime.h>
#include <math.h>

#define NB 8
#define NS 4
#define NP 4096
#define HID 4096
#define NHQ 32
#define NHKV 8
#define ND 128
#define NGROUP 4
#define NBS 32      /* NB*NS rows */
#define NQI 16      /* NGROUP*NS q-rows per (b,kv) */
#define NCHUNK 17   /* 16 cache chunks of 256 + 1 new-token chunk */
#define TCHUNK 256
#define QKV_COLS 6144
#define KSPLIT 16
#define KSLICE 256  /* 4096 / KSPLIT */
#define GRID_PRE 768
#define LOG2E 1.4426950408889634f

// -------- async global -> LDS (16 B/lane; LDS base wave-uniform, global
// source per-lane) --------
__device__ __forceinline__ void gl_lds16(const float* g, float* l) {
  __builtin_amdgcn_global_load_lds(
      (const __attribute__((address_space(1))) void*)g,
      (__attribute__((address_space(3))) void*)l, 16, 0, 0);
}

// -------- grid-wide barrier: all blocks resident (grid == 3/CU x 256 CUs) --
// arrive/release counters zeroed by hipMemsetAsync before launch.
__device__ __forceinline__ void gsync(unsigned* arrive, unsigned* release,
                                      unsigned gen, int nblk) {
  __syncthreads();  // drains vmcnt/lgkmcnt for this block's waves
  if (threadIdx.x == 0) {
    __threadfence();  // device-scope release of this block's writes
    unsigned old = atomicAdd(arrive, 1u);
    if (old == (unsigned)(nblk - 1)) {
      atomicExch(arrive, 0u);  // reset before release; nobody touches arrive
      __threadfence();         // until they pass this barrier
      atomicAdd(release, 1u);
    } else {
      while (atomicAdd(release, 0u) < gen) __builtin_amdgcn_s_sleep(2);
    }
    __threadfence();  // acquire
  }
  __syncthreads();
}

// -------- GEMM stage: P[kb][32][ncols] tile (128 cols x KSLICE k) ----------
// W staged via global_load_lds in 8-row chunks (4 KB), double-buffered,
// counted vmcnt(1) so the next chunk's loads stay in flight across barriers.
// Wave wid owns m-rows wid*8..+8; lanes cover 128 cols as float2.
__device__ __forceinline__ void gemm_stage(const float* __restrict__ A_T,
                                           const float* __restrict__ Wc,
                                           int ld, float* __restrict__ P,
                                           int ncols, int col0, int kb,
                                           float* xs, float* wbuf) {
  int tid = threadIdx.x;
  int lane = tid & 63;
  int wid = __builtin_amdgcn_readfirstlane(tid >> 6);
  int kblk = kb * KSLICE;
  const float* wbase = Wc + (size_t)kblk * ld;
  int wrow = 2 * wid + (lane >> 5);      // 2 rows per wave per chunk
  int wcol = (lane & 31) * 4;
  const float* wsrc = wbase + (size_t)wrow * ld + wcol;

  // prologue: x-slice (KSLICE x 32 = 32 KB; 8 instr/wave), then W chunks 0,1
#pragma unroll
  for (int j = 0; j < 8; j++) {
    int off = wid * 2048 + j * 256;  // floats; wave-uniform LDS base
    gl_lds16(A_T + (size_t)kblk * NBS + off + lane * 4, xs + off);
  }
  gl_lds16(wsrc, wbuf + wrow * 128);
  gl_lds16(wsrc + (size_t)8 * ld, wbuf + 1024 + wrow * 128);

  float acc[8][2];
#pragma unroll
  for (int m = 0; m < 8; m++) acc[m][0] = acc[m][1] = 0.f;

  constexpr int NCH = KSLICE / 8;  // 32 chunks
#pragma unroll 1
  for (int c = 0; c < NCH; c++) {
    if (c < NCH - 1)
      asm volatile("s_waitcnt vmcnt(1)" ::: "memory");
    else
      asm volatile("s_waitcnt vmcnt(0)" ::: "memory");
    __builtin_amdgcn_s_barrier();
    asm volatile("" ::: "memory");

    const float* wbp = wbuf + (c & 1) * 1024;
    const float* xcp = xs + c * 256 + wid * 8;
#pragma unroll
    for (int k = 0; k < 8; k++) {
      float2 w2 = *(const float2*)(wbp + k * 128 + lane * 2);
      float4 xa = *(const float4*)(xcp + k * 32);      // wave-uniform
      float4 xb = *(const float4*)(xcp + k * 32 + 4);  // broadcast reads
      float xm[8] = {xa.x, xa.y, xa.z, xa.w, xb.x, xb.y, xb.z, xb.w};
#pragma unroll
      for (int m = 0; m < 8; m++) {
        acc[m][0] = fmaf(xm[m], w2.x, acc[m][0]);
        acc[m][1] = fmaf(xm[m], w2.y, acc[m][1]);
      }
    }

    asm volatile("" ::: "memory");
    __builtin_amdgcn_s_barrier();
    if (c + 2 < NCH)
      gl_lds16(wsrc + (size_t)((c + 2) * 8) * ld,
               wbuf + (c & 1) * 1024 + wrow * 128);
  }

#pragma unroll
  for (int m = 0; m < 8; m++)
    *(float2*)(P + ((size_t)kb * NBS + wid * 8 + m) * ncols + col0 +
               lane * 2) = make_float2(acc[m][0], acc[m][1]);
}

// ======================= K1: xT -> QKV GEMM -> reduce+RoPE =================
__global__ __launch_bounds__(256, 4) void k_pre(
    const float* __restrict__ x, const float* __restrict__ wq,
    const float* __restrict__ wk, const float* __restrict__ wv,
    const float* __restrict__ cosp, const float* __restrict__ sinp,
    const int* __restrict__ past_len, float* __restrict__ xT,
    float* __restrict__ Pq, float* __restrict__ q_t,
    float* __restrict__ k_new, float* __restrict__ vbuf,
    unsigned* __restrict__ bar) {
  __shared__ __align__(16) float lds[KSLICE * NBS + 2 * 8 * 128];  // 40 KB
  int bid = blockIdx.x;
  int tid = threadIdx.x;
  int gid = bid * 256 + tid;

  // ---- stage 0: transpose x (32 x 4096) -> xT (4096 x 32) ----
  if (gid < NBS * HID) {
    int r = gid >> 12, k = gid & 4095;
    xT[k * NBS + r] = x[gid];
  }
  gsync(bar, bar + 1, 1, GRID_PRE);

  // ---- stage 1: QKV GEMM partials (48 col-tiles x 16 ksplit = 768) ----
  {
    int cb = bid >> 4, kb = bid & 15;
    int col0 = cb * 128;
    const float* Wc;
    int ld;
    if (col0 < 4096) {
      Wc = wq + col0; ld = 4096;
    } else if (col0 < 5120) {
      Wc = wk + (col0 - 4096); ld = 1024;
    } else {
      Wc = wv + (col0 - 5120); ld = 1024;
    }
    gemm_stage(xT, Wc, ld, Pq, QKV_COLS, col0, kb, lds, lds + KSLICE * NBS);
  }
  gsync(bar, bar + 1, 2, GRID_PRE);

  // ---- stage 2: reduce 16 partials + RoPE, write q_t/k_new/vbuf ----
  // 196608 elements == grid*256 exactly; rope partner (d^64) is gid^64,
  // always within the same block -> LDS exchange.
  {
    float s = 0.f;
#pragma unroll
    for (int p = 0; p < KSPLIT; p++)
      s += Pq[(size_t)p * (NBS * QKV_COLS) + gid];
    lds[tid] = s;
    __syncthreads();
    float other = lds[tid ^ 64];
    int r = gid / QKV_COLS;
    int col = gid - r * QKV_COLS;
    int b = r >> 2, si = r & 3;
    int pos = past_len[0] + si;
    if (col < 4096) {  // q
      int h = col >> 7, d = col & 127;
      float c = cosp[pos * ND + d], sn = sinp[pos * ND + d];
      float oth = (d < 64) ? -other : other;
      int kv = h >> 2, g = h & 3;
      q_t[(((b * NHKV + kv) * ND + d) * NQI) + g * NS + si] =
          fmaf(s, c, oth * sn);
    } else if (col < 5120) {  // k
      int cc = col - 4096;
      int kv = cc >> 7, d = cc & 127;
      float c = cosp[pos * ND + d], sn = sinp[pos * ND + d];
      float oth = (d < 64) ? -other : other;
      k_new[((b * NHKV + kv) * NS + si) * ND + d] = fmaf(s, c, oth * sn);
    } else {  // v
      vbuf[(size_t)r * 1024 + (col - 5120)] = s;
    }
  }
}

// ---------------- attention: round-0 structure (best measured) -------------
__global__ __launch_bounds__(256) void attn_kernel(
    const float* __restrict__ q_t, const float* __restrict__ k_cache,
    const float* __restrict__ v_cache, const float* __restrict__ k_new,
    const float* __restrict__ vbuf, float* __restrict__ part_o,
    float* __restrict__ part_m, float* __restrict__ part_l) {
  __shared__ float p_lds[TCHUNK * 17];  // stride 17: conflict-free
  __shared__ float redm[NQI][4];
  __shared__ float redl[NQI][4];
  __shared__ float mfin[NQI];
  int bk = blockIdx.x;
  int chunk = blockIdx.y;
  int blk = bk * NCHUNK + chunk;
  int b = bk >> 3, kv = bk & 7;
  int tid = threadIdx.x;
  int lane = tid & 63;
  int wid = tid >> 6;
  bool last = (chunk == NCHUNK - 1);
  int tcount = last ? NS : TCHUNK;
  const float* qbase = q_t + (size_t)bk * (ND * NQI);

  // ---- scores: one thread per t, full d ----
  int t_loc = tid;
  bool valid = t_loc < tcount;
  int t_eff = valid ? t_loc : 0;
  const float* kp =
      last ? (k_new + ((size_t)bk * NS + t_eff) * ND)
           : (k_cache +
              (((size_t)b * NP + chunk * TCHUNK + t_eff) * NHKV + kv) * ND);
  float s_acc[NQI];
#pragma unroll
  for (int i = 0; i < NQI; i++) s_acc[i] = 0.f;
#pragma unroll 8
  for (int d4 = 0; d4 < 32; ++d4) {
    float4 kvv = *(const float4*)(kp + d4 * 4);
    const float* qp = qbase + (d4 * 4) * NQI;  // uniform -> s_load
#pragma unroll
    for (int i = 0; i < NQI; i++) {
      float s = s_acc[i];
      s = fmaf(kvv.x, qp[i], s);
      s = fmaf(kvv.y, qp[NQI + i], s);
      s = fmaf(kvv.z, qp[2 * NQI + i], s);
      s = fmaf(kvv.w, qp[3 * NQI + i], s);
      s_acc[i] = s;
    }
  }
  const float scale = 0.08838834764831845f;  // 1/sqrt(128)
  float sc[NQI];
#pragma unroll
  for (int i = 0; i < NQI; i++) {
    float s = s_acc[i] * scale;
    if (!valid || (last && t_loc > (i & 3))) s = -__builtin_inff();
    sc[i] = s;
  }
#pragma unroll
  for (int i = 0; i < NQI; i++) {
    float m = sc[i];
#pragma unroll
    for (int off = 1; off < 64; off <<= 1) m = fmaxf(m, __shfl_xor(m, off, 64));
    if (lane == 0) redm[i][wid] = m;
  }
  __syncthreads();
  if (tid < NQI) {
    float m = fmaxf(fmaxf(redm[tid][0], redm[tid][1]),
                    fmaxf(redm[tid][2], redm[tid][3]));
    mfin[tid] = m;
  }
  __syncthreads();
  float l_loc[NQI];
#pragma unroll
  for (int i = 0; i < NQI; i++) {
    float p = exp2f((sc[i] - mfin[i]) * LOG2E);
    p_lds[t_loc * 17 + i] = p;
    l_loc[i] = p;
  }
#pragma unroll
  for (int i = 0; i < NQI; i++) {
    float l = l_loc[i];
#pragma unroll
    for (int off = 1; off < 64; off <<= 1) l += __shfl_xor(l, off, 64);
    if (lane == 0) redl[i][wid] = l;
  }
  __syncthreads();
  if (tid < NQI) {
    float l = redl[tid][0] + redl[tid][1] + redl[tid][2] + redl[tid][3];
    part_m[(size_t)blk * NQI + tid] = mfin[tid];
    part_l[(size_t)blk * NQI + tid] = l;
  }

  // ---- PV: thread -> 2 q-rows (r0, r0+8) x 4 d ----
  int r0 = tid >> 5;
  int dq = (tid & 31) * 4;
  const float* vpb =
      last ? (vbuf + (size_t)b * NS * (NHKV * ND) + kv * ND + dq)
           : (v_cache + ((size_t)b * NP + chunk * TCHUNK) * (NHKV * ND) +
              kv * ND + dq);
  float o0[4] = {0, 0, 0, 0}, o1[4] = {0, 0, 0, 0};
#pragma unroll 8
  for (int t = 0; t < tcount; ++t) {
    float4 vv = *(const float4*)(vpb + (size_t)t * (NHKV * ND));
    float p0 = p_lds[t * 17 + r0];
    float p1 = p_lds[t * 17 + r0 + 8];
    o0[0] = fmaf(p0, vv.x, o0[0]); o0[1] = fmaf(p0, vv.y, o0[1]);
    o0[2] = fmaf(p0, vv.z, o0[2]); o0[3] = fmaf(p0, vv.w, o0[3]);
    o1[0] = fmaf(p1, vv.x, o1[0]); o1[1] = fmaf(p1, vv.y, o1[1]);
    o1[2] = fmaf(p1, vv.z, o1[2]); o1[3] = fmaf(p1, vv.w, o1[3]);
  }
  size_t obase = (size_t)blk * (NQI * ND);
  *(float4*)(part_o + obase + (size_t)r0 * ND + dq) =
      make_float4(o0[0], o0[1], o0[2], o0[3]);
  *(float4*)(part_o + obase + (size_t)(r0 + 8) * ND + dq) =
      make_float4(o1[0], o1[1], o1[2], o1[3]);
}

// ======================= K3: combine -> O GEMM -> reduce ===================
__global__ __launch_bounds__(256, 4) void k_post(
    const float* __restrict__ part_o, const float* __restrict__ part_m,
    const float* __restrict__ part_l, const float* __restrict__ wo,
    float* __restrict__ attn_T, float* __restrict__ Po,
    float* __restrict__ out, unsigned* __restrict__ bar) {
  __shared__ __align__(16) float lds[KSLICE * NBS + 2 * 8 * 128];
  int bid = blockIdx.x, tid = threadIdx.x;
  int gid = bid * 256 + tid;

  // ---- stage 0: combine partials -> attn_T (32768 workers) ----
  if (gid < 32768) {
    int bk = gid >> 9;
    int i = (gid >> 5) & 15;
    int dh = (gid & 31) * 4;
    float M = -__builtin_inff();
#pragma unroll
    for (int c = 0; c < NCHUNK; c++)
      M = fmaxf(M, part_m[((size_t)bk * NCHUNK + c) * NQI + i]);
    float L = 0.f, o0 = 0.f, o1 = 0.f, o2 = 0.f, o3 = 0.f;
#pragma unroll
    for (int c = 0; c < NCHUNK; c++) {
      size_t pc = (size_t)bk * NCHUNK + c;
      float w = exp2f((part_m[pc * NQI + i] - M) * LOG2E);
      L = fmaf(part_l[pc * NQI + i], w, L);
      float4 po =
          *(const float4*)(part_o + pc * (NQI * ND) + (size_t)i * ND + dh);
      o0 = fmaf(w, po.x, o0);
      o1 = fmaf(w, po.y, o1);
      o2 = fmaf(w, po.z, o2);
      o3 = fmaf(w, po.w, o3);
    }
    float inv = 1.0f / L;
    int b = bk >> 3, kv = bk & 7;
    int g = i >> 2, si = i & 3;
    int h = kv * NGROUP + g;
    int r = b * NS + si;
    attn_T[(size_t)(h * ND + dh + 0) * NBS + r] = o0 * inv;
    attn_T[(size_t)(h * ND + dh + 1) * NBS + r] = o1 * inv;
    attn_T[(size_t)(h * ND + dh + 2) * NBS + r] = o2 * inv;
    attn_T[(size_t)(h * ND + dh + 3) * NBS + r] = o3 * inv;
  }
  gsync(bar, bar + 1, 1, GRID_PRE);

  // ---- stage 1: O GEMM partials (32 col-tiles x 16 ksplit = 512 active) ---
  if (bid < 512) {
    int cb = bid >> 4, kb = bid & 15;
    int col0 = cb * 128;
    gemm_stage(attn_T, wo + col0, 4096, Po, 4096, col0, kb, lds,
               lds + KSLICE * NBS);
  }
  gsync(bar, bar + 1, 2, GRID_PRE);

  // ---- stage 2: reduce 16 partials -> out (32768 float4 workers) ----
  if (gid < 32768) {
    size_t idx = (size_t)gid * 4;
    float4 s4 = make_float4(0.f, 0.f, 0.f, 0.f);
#pragma unroll
    for (int p = 0; p < KSPLIT; p++) {
      float4 v = *(const float4*)(Po + (size_t)p * (NBS * 4096) + idx);
      s4.x += v.x; s4.y += v.y; s4.z += v.z; s4.w += v.w;
    }
    *(float4*)(out + idx) = s4;
  }
}

// ---------------------------------------------------------------------------
extern "C" void kernel_launch(void* const* d_in, const int* in_sizes, int n_in,
                              void* d_out, int out_size, void* d_ws,
                              size_t ws_size, hipStream_t stream) {
  const float* x = (const float*)d_in[0];
  const float* wq = (const float*)d_in[1];
  const float* wk = (const float*)d_in[2];
  const float* wv = (const float*)d_in[3];
  const float* wo = (const float*)d_in[4];
  const float* cosp = (const float*)d_in[5];
  const float* sinp = (const float*)d_in[6];
  const float* k_cache = (const float*)d_in[7];
  const float* v_cache = (const float*)d_in[8];
  const int* past_len = (const int*)d_in[9];
  float* out = (float*)d_out;

  float* ws = (float*)d_ws;
  float* xT = ws;                   // 131072
  float* q_t = xT + 131072;         // 131072
  float* k_new = q_t + 131072;      // 32768
  float* vbuf = k_new + 32768;      // 32768
  float* attn_T = vbuf + 32768;     // 131072
  unsigned* bar = (unsigned*)(attn_T + 131072);  // 16 floats reserved
  float* R = attn_T + 131072 + 16;  // shared region
  float* Pq = R;                    // 16*32*6144 = 3145728 (dead after K1.s2)
  float* part_o = R;                // 64*17*2048 = 2228224 (dead after K3.s0)
  float* part_m = R + 2228224;      // 17408
  float* part_l = part_m + 17408;   // 17408
  float* Po = R;                    // 16*32*4096 = 2097152 (< 2228224: never
                                    //  touches part_m/l, which are dead then)
  // total ws: 3604496 floats = 14.42 MB (proven available since round 0)

  hipMemsetAsync(bar, 0, 16, stream);  // zero both barrier pairs
  k_pre<<<GRID_PRE, 256, 0, stream>>>(x, wq, wk, wv, cosp, sinp, past_len, xT,
                                      Pq, q_t, k_new, vbuf, bar);
  attn_kernel<<<dim3(64, NCHUNK), 256, 0, stream>>>(
      q_t, k_cache, v_cache, k_new, vbuf, part_o, part_m, part_l);
  k_post<<<GRID_PRE, 256, 0, stream>>>(part_o, part_m, part_l, wo, attn_T, Po,
                                       out, bar + 2);
}